// Round 5
// baseline (3994.323 us; speedup 1.0000x reference)
//
#include <hip/hip_runtime.h>
#include <stdint.h>

#define K_DIM 4096
#define N_DIM 11008
#define M_DIM 8192

constexpr int BM = 128, BN = 128, BK = 64;
constexpr int NT  = K_DIM / BK;    // 64
constexpr int NZW = N_DIM / 8;     // 1376
constexpr int NXT = N_DIM / BN;    // 86
constexpr int MXT = M_DIM / BM;    // 64
constexpr int NWG = NXT * MXT;     // 5504 = 8 * 688

typedef _Float16 f16x2 __attribute__((ext_vector_type(2)));
typedef _Float16 f16x8 __attribute__((ext_vector_type(8)));
typedef float    f32x4 __attribute__((ext_vector_type(4)));
union H8 { f16x8 v; f16x2 p[4]; };

// word w holds nibbles for k-offsets 0..7; output k-order (0,4,1,5,2,6,3,7).
// Exact: (1024+q) - (1024+z) is Sterbenz-exact; single rounding on *s.
__device__ __forceinline__ f16x8 dq_word(uint32_t w, f16x2 ss, f16x2 zz) {
    H8 r;
    uint32_t t0 = ( w        & 0x000F000Fu) | 0x64006400u;
    uint32_t t1 = ((w >> 4)  & 0x000F000Fu) | 0x64006400u;
    uint32_t t2 = ((w >> 8)  & 0x000F000Fu) | 0x64006400u;
    uint32_t t3 = ((w >> 12) & 0x000F000Fu) | 0x64006400u;
    r.p[0] = (__builtin_bit_cast(f16x2, t0) - zz) * ss;
    r.p[1] = (__builtin_bit_cast(f16x2, t1) - zz) * ss;
    r.p[2] = (__builtin_bit_cast(f16x2, t2) - zz) * ss;
    r.p[3] = (__builtin_bit_cast(f16x2, t3) - zz) * ss;
    return r.v;
}

// ================= pre-pass: x fp32 -> f16, fragment-major tiles =================
// x16 layout: [mt(64)][kt(64)][frag fk(8)][row(128)][8 f16 permuted octet]
// fk = ks*4+lk covers k = kt*64 + fk*8 + {0..7}; octet stored as pairs (e, e+4).
__global__ __launch_bounds__(1024)
void prep_kernel(const float* __restrict__ x, _Float16* __restrict__ x16) {
    const int b  = blockIdx.x;          // mt*64 + kt
    const int mt = b >> 6, kt = b & 63;
    const int t  = threadIdx.x;         // fk*128 + row
    const int row = t & 127, fk = t >> 7;
    const float* src = x + (size_t)(mt * 128 + row) * K_DIM + kt * 64 + fk * 8;
    f32x4 a0 = *(const f32x4*)src;
    f32x4 a1 = *(const f32x4*)(src + 4);
    H8 v;
#pragma unroll
    for (int j = 0; j < 4; ++j)
        v.p[j] = __builtin_bit_cast(f16x2, __builtin_amdgcn_cvt_pkrtz(a0[j], a1[j]));
    *(f16x8*)(x16 + (size_t)b * 8192 + t * 8) = v.v;
}

// ======== main kernel: A reg-staged (flat loads -> ds_write), dbuf, 1 barrier/tile ========
__global__ __launch_bounds__(256, 3)
void qgemm3_kernel(const _Float16* __restrict__ x16, const uint32_t* __restrict__ qw,
                   const uint32_t* __restrict__ qz, const float* __restrict__ sc,
                   const float* __restrict__ bias, float* __restrict__ out)
{
    __shared__ _Float16 As[2 * 8192];   // 2 x 16 KiB, fragment-major, linear

    const int tid = threadIdx.x;
    const int lid = (blockIdx.x & 7) * (NWG / 8) + (blockIdx.x >> 3); // XCD swizzle
    const int mt  = lid / NXT;
    const int n0  = (lid % NXT) * BN;

    const int lane = tid & 63, wid = tid >> 6;
    const int wr = wid >> 1, wc = wid & 1;
    const int lr = lane & 15, lk = lane >> 4;

    f32x4 acc[4][4];
#pragma unroll
    for (int i = 0; i < 4; ++i)
#pragma unroll
        for (int j = 0; j < 4; ++j) {
            f32x4 z = {0.f, 0.f, 0.f, 0.f};
            acc[i][j] = z;
        }

    const int ncb = n0 + wc * 64 + lr;
    const int shz = 4 * (lr & 7);

    const _Float16* xsrc = x16 + (size_t)mt * 64 * 8192 + tid * 8;
    const uint32_t* qp0 = qw + (size_t)lk * N_DIM + ncb;
    const uint32_t* qp1 = qp0 + (size_t)4 * N_DIM;

    f16x8    a0, a1, a2, a3;            // in-flight A tile (named, never indexed)
    uint32_t breg[2][8];
    float    s_nxt[4];
    uint32_t z_nxt[4];
    f16x2    ssv[4], zzv[4];

#define A_LOAD(KT) do {                                                      \
    const _Float16* s_ = xsrc + (size_t)(KT) * 8192;                         \
    a0 = *(const f16x8*)(s_);                                                \
    a1 = *(const f16x8*)(s_ + 2048);                                         \
    a2 = *(const f16x8*)(s_ + 4096);                                         \
    a3 = *(const f16x8*)(s_ + 6144); } while (0)

#define A_WRITE(BUF) do {                                                    \
    _Float16* d_ = &As[(BUF) * 8192 + tid * 8];                              \
    *(f16x8*)(d_)        = a0;                                               \
    *(f16x8*)(d_ + 2048) = a1;                                               \
    *(f16x8*)(d_ + 4096) = a2;                                               \
    *(f16x8*)(d_ + 6144) = a3; } while (0)

#define LOADB(BUF) do {                                                      \
    _Pragma("unroll") for (int j = 0; j < 4; ++j) breg[BUF][j]     = qp0[j * 16]; \
    _Pragma("unroll") for (int j = 0; j < 4; ++j) breg[BUF][4 + j] = qp1[j * 16]; \
    qp0 += (size_t)8 * N_DIM; qp1 += (size_t)8 * N_DIM; } while (0)

#define LOADSZ(g) do { _Pragma("unroll") for (int j = 0; j < 4; ++j) {       \
    s_nxt[j] = sc[(size_t)(g) * N_DIM + ncb + j * 16];                       \
    z_nxt[j] = qz[(size_t)(g) * NZW + (ncb >> 3) + j * 2]; } } while (0)

#define MAKESZ() do { _Pragma("unroll") for (int j = 0; j < 4; ++j) {        \
    _Float16 zh = (_Float16)(float)(1024u + ((z_nxt[j] >> shz) & 15u));      \
    _Float16 sh = (_Float16)s_nxt[j];                                        \
    f16x2 sp = {sh, sh}; ssv[j] = sp;                                        \
    f16x2 zp = {zh, zh}; zzv[j] = zp; } } while (0)

#define COMPUTE(BUF) do {                                                    \
    const int abase_ = (BUF) * 8192 + (wr * 64 + lr) * 8;                    \
    _Pragma("unroll") for (int ks = 0; ks < 2; ++ks) {                       \
        f16x8 af[4], bf[4];                                                  \
        _Pragma("unroll") for (int i = 0; i < 4; ++i)                        \
            af[i] = *(const f16x8*)&As[abase_ + (ks * 4 + lk) * 1024 + i * 128]; \
        _Pragma("unroll") for (int j = 0; j < 4; ++j)                        \
            bf[j] = dq_word(breg[BUF][ks * 4 + j], ssv[j], zzv[j]);          \
        _Pragma("unroll") for (int i = 0; i < 4; ++i)                        \
            _Pragma("unroll") for (int j = 0; j < 4; ++j)                    \
                acc[i][j] = __builtin_amdgcn_mfma_f32_16x16x32_f16(af[i], bf[j], acc[i][j], 0, 0, 0); \
    } } while (0)

    // ---------------- prologue: tile 0 -> buf0, B(0) -> breg[0], group 0 ----------------
    LOADSZ(0);
    A_LOAD(0);
    LOADB(0);
    MAKESZ();
    A_WRITE(0);
    __syncthreads();

    for (int kt2 = 0; kt2 < NT / 2; ++kt2) {
        const int kt = kt2 * 2;
        // phase A (tile kt, always has a successor kt+1 <= 63):
        A_LOAD(kt + 1);         // issue early — lands during COMPUTE
        LOADB(1);               // B(kt+1) in flight during COMPUTE
        COMPUTE(0);             // buf0, breg[0]
        A_WRITE(1);             // write late (vmcnt wait hidden by COMPUTE)
        __syncthreads();

        // phase B (tile kt+1):
        if (kt2 + 1 < NT / 2) {
            A_LOAD(kt + 2);
            LOADB(0);
            LOADSZ(kt2 + 1);    // next group's raw s/z
            COMPUTE(1);         // buf1, breg[1] (uses group kt2's ssv/zzv)
            A_WRITE(0);
            MAKESZ();           // group kt2+1, after COMPUTE(1) consumed old ssv/zzv
        } else {
            COMPUTE(1);
        }
        __syncthreads();
    }

#undef A_LOAD
#undef A_WRITE
#undef LOADB
#undef LOADSZ
#undef MAKESZ
#undef COMPUTE

    // epilogue: C/D layout col = lane&15, row = (lane>>4)*4 + reg
    const int ccol0 = n0 + wc * 64 + lr;
    float bj[4];
#pragma unroll
    for (int j = 0; j < 4; ++j) bj[j] = bias[ccol0 + j * 16];
    const int m0 = mt * BM;
#pragma unroll
    for (int i = 0; i < 4; ++i) {
        const int rbase = m0 + wr * 64 + i * 16 + lk * 4;
#pragma unroll
        for (int j = 0; j < 4; ++j) {
            const int col = ccol0 + j * 16;
#pragma unroll
            for (int r = 0; r < 4; ++r)
                out[(size_t)(rbase + r) * N_DIM + col] = acc[i][j][r] + bj[j];
        }
    }
}

// ================= fallback (R2 kernel) for small ws =================
constexpr int LDA_FB = 72;
__global__ __launch_bounds__(256, 3)
void qgemm_fb_kernel(const float* __restrict__ x, const uint32_t* __restrict__ qw,
                     const uint32_t* __restrict__ qz, const float* __restrict__ sc,
                     const float* __restrict__ bias, float* __restrict__ out)
{
    __shared__ _Float16 As[BM * LDA_FB];
    const int tid  = threadIdx.x;
    const int lid  = (blockIdx.x & 7) * (NWG / 8) + (blockIdx.x >> 3);
    const int m0   = (lid / NXT) * BM;
    const int n0   = (lid % NXT) * BN;
    const int lane = tid & 63, wid = tid >> 6;
    const int wr = wid >> 1, wc = wid & 1;
    const int lr = lane & 15, lk = lane >> 4;
    const int arow = tid >> 3, acp = tid & 7;

    f32x4 acc[4][4];
#pragma unroll
    for (int i = 0; i < 4; ++i)
#pragma unroll
        for (int j = 0; j < 4; ++j) { f32x4 z = {0.f,0.f,0.f,0.f}; acc[i][j] = z; }

    f32x4 areg[4][2];
    uint32_t breg[8], bregN[8];
    f16x2 ssv[4], zzv[4];
    float s_nxt[4]; uint32_t z_nxt[4];
    const int ncb = n0 + wc * 64 + lr;
    const int shz = 4 * (lr & 7);
    const float* xbase = x + (size_t)(m0 + arow) * K_DIM + acp * 8;

#pragma unroll
    for (int i = 0; i < 4; ++i) {
        const float* src = xbase + (size_t)(i * 32) * K_DIM;
        areg[i][0] = *(const f32x4*)(src);
        areg[i][1] = *(const f32x4*)(src + 4);
    }
    {
        const uint32_t* pB = qw + (size_t)lk * N_DIM + ncb;
#pragma unroll
        for (int j = 0; j < 4; ++j) bregN[j]     = pB[j * 16];
#pragma unroll
        for (int j = 0; j < 4; ++j) bregN[4 + j] = pB[(size_t)4 * N_DIM + j * 16];
    }
#pragma unroll
    for (int j = 0; j < 4; ++j) {
        s_nxt[j] = sc[ncb + j * 16];
        z_nxt[j] = qz[(ncb >> 3) + j * 2];
    }

    for (int kt = 0; kt < NT; ++kt) {
        if ((kt & 1) == 0) {
#pragma unroll
            for (int j = 0; j < 4; ++j) {
                _Float16 zh = (_Float16)(float)(1024u + ((z_nxt[j] >> shz) & 15u));
                _Float16 sh = (_Float16)s_nxt[j];
                f16x2 zp = {zh, zh}; zzv[j] = zp;
                f16x2 sp = {sh, sh}; ssv[j] = sp;
            }
        }
        __syncthreads();
#pragma unroll
        for (int i = 0; i < 4; ++i) {
            H8 v;
#pragma unroll
            for (int j = 0; j < 4; ++j)
                v.p[j] = __builtin_bit_cast(f16x2,
                           __builtin_amdgcn_cvt_pkrtz(areg[i][0][j], areg[i][1][j]));
            *(f16x8*)&As[(arow + i * 32) * LDA_FB + acp * 8] = v.v;
        }
        __syncthreads();
#pragma unroll
        for (int q = 0; q < 8; ++q) breg[q] = bregN[q];
        if (kt + 1 < NT) {
            const float* ap = xbase + (kt + 1) * BK;
#pragma unroll
            for (int i = 0; i < 4; ++i) {
                const float* src = ap + (size_t)(i * 32) * K_DIM;
                areg[i][0] = *(const f32x4*)(src);
                areg[i][1] = *(const f32x4*)(src + 4);
            }
            const uint32_t* pBn = qw + (size_t)((kt + 1) * 8 + lk) * N_DIM + ncb;
#pragma unroll
            for (int j = 0; j < 4; ++j) bregN[j]     = pBn[j * 16];
#pragma unroll
            for (int j = 0; j < 4; ++j) bregN[4 + j] = pBn[(size_t)4 * N_DIM + j * 16];
            if (kt & 1) {
                const int g = (kt + 1) >> 1;
#pragma unroll
                for (int j = 0; j < 4; ++j) {
                    s_nxt[j] = sc[(size_t)g * N_DIM + ncb + j * 16];
                    z_nxt[j] = qz[(size_t)g * NZW + (ncb >> 3) + j * 2];
                }
            }
        }
#pragma unroll
        for (int ks = 0; ks < 2; ++ks) {
            f16x8 af[4], bf[4];
#pragma unroll
            for (int i = 0; i < 4; ++i)
                af[i] = *(const f16x8*)&As[(wr * 64 + i * 16 + lr) * LDA_FB + ks * 32 + lk * 8];
#pragma unroll
            for (int j = 0; j < 4; ++j)
                bf[j] = dq_word(breg[ks * 4 + j], ssv[j], zzv[j]);
#pragma unroll
            for (int i = 0; i < 4; ++i)
#pragma unroll
                for (int j = 0; j < 4; ++j)
                    acc[i][j] = __builtin_amdgcn_mfma_f32_16x16x32_f16(af[i], bf[j], acc[i][j], 0, 0, 0);
        }
    }
    const int ccol0 = n0 + wc * 64 + lr;
    float bj[4];
#pragma unroll
    for (int j = 0; j < 4; ++j) bj[j] = bias[ccol0 + j * 16];
#pragma unroll
    for (int i = 0; i < 4; ++i) {
        const int rbase = m0 + wr * 64 + i * 16 + lk * 4;
#pragma unroll
        for (int j = 0; j < 4; ++j) {
            const int col = ccol0 + j * 16;
#pragma unroll
            for (int r = 0; r < 4; ++r)
                out[(size_t)(rbase + r) * N_DIM + col] = acc[i][j][r] + bj[j];
        }
    }
}

extern "C" void kernel_launch(void* const* d_in, const int* in_sizes, int n_in,
                              void* d_out, int out_size, void* d_ws, size_t ws_size,
                              hipStream_t stream) {
    const float*    xp = (const float*)d_in[0];
    const uint32_t* qw = (const uint32_t*)d_in[1];
    const uint32_t* qz = (const uint32_t*)d_in[2];
    const float*    sc = (const float*)d_in[3];
    const float*    bi = (const float*)d_in[4];
    float*          op = (float*)d_out;
    (void)in_sizes; (void)n_in; (void)out_size;

    const size_t need = (size_t)M_DIM * K_DIM * sizeof(_Float16); // 64 MiB
    if (ws_size >= need) {
        prep_kernel<<<dim3(MXT * NT), dim3(1024), 0, stream>>>(xp, (_Float16*)d_ws);
        qgemm3_kernel<<<dim3(NWG), dim3(256), 0, stream>>>((const _Float16*)d_ws, qw, qz, sc, bi, op);
    } else {
        qgemm_fb_kernel<<<dim3(NWG), dim3(256), 0, stream>>>(xp, qw, qz, sc, bi, op);
    }
}

// Round 6
// 1002.162 us; speedup vs baseline: 3.9857x; 3.9857x over previous
//
#include <hip/hip_runtime.h>
#include <stdint.h>

#define K_DIM 4096
#define N_DIM 11008
#define M_DIM 8192

constexpr int BM = 128, BN = 128, BK = 64;
constexpr int LDA = 72;            // f16 elems/row: 144 B stride (R2-proven)
constexpr int NT  = K_DIM / BK;    // 64
constexpr int NZW = N_DIM / 8;     // 1376
constexpr int NXT = N_DIM / BN;    // 86
constexpr int MXT = M_DIM / BM;    // 64
constexpr int NWG = NXT * MXT;     // 5504 = 8 * 688

typedef _Float16 f16x2 __attribute__((ext_vector_type(2)));
typedef _Float16 f16x8 __attribute__((ext_vector_type(8)));
typedef float    f32x4 __attribute__((ext_vector_type(4)));
union H8 { f16x8 v; f16x2 p[4]; };

// word w holds nibbles for k-offsets 0..7; output k-order (0,4,1,5,2,6,3,7).
// Exact: (1024+q) - (1024+z) is Sterbenz-exact; single rounding on *s.
__device__ __forceinline__ f16x8 dq_word(uint32_t w, f16x2 ss, f16x2 zz) {
    H8 r;
    uint32_t t0 = ( w        & 0x000F000Fu) | 0x64006400u;
    uint32_t t1 = ((w >> 4)  & 0x000F000Fu) | 0x64006400u;
    uint32_t t2 = ((w >> 8)  & 0x000F000Fu) | 0x64006400u;
    uint32_t t3 = ((w >> 12) & 0x000F000Fu) | 0x64006400u;
    r.p[0] = (__builtin_bit_cast(f16x2, t0) - zz) * ss;
    r.p[1] = (__builtin_bit_cast(f16x2, t1) - zz) * ss;
    r.p[2] = (__builtin_bit_cast(f16x2, t2) - zz) * ss;
    r.p[3] = (__builtin_bit_cast(f16x2, t3) - zz) * ss;
    return r.v;
}

// ===== R2 structure + LDS double-buffer (1 barrier/tile) + T14 load/write split =====
__global__ __launch_bounds__(256, 3)
void qgemm_kernel(const float* __restrict__ x, const uint32_t* __restrict__ qw,
                  const uint32_t* __restrict__ qz, const float* __restrict__ sc,
                  const float* __restrict__ bias, float* __restrict__ out)
{
    __shared__ _Float16 As[2][BM * LDA];   // 2 x 18 KiB

    const int tid  = threadIdx.x;
    const int lid  = (blockIdx.x & 7) * (NWG / 8) + (blockIdx.x >> 3); // XCD swizzle
    const int m0   = (lid / NXT) * BM;
    const int n0   = (lid % NXT) * BN;

    const int lane = tid & 63, wid = tid >> 6;
    const int wr = wid >> 1, wc = wid & 1;
    const int lr = lane & 15, lk = lane >> 4;

    const int arow = tid >> 3;        // A staging row (0..31, +i*32)
    const int acp  = tid & 7;         // A staging col-octet

    f32x4 acc[4][4];
#pragma unroll
    for (int i = 0; i < 4; ++i)
#pragma unroll
        for (int j = 0; j < 4; ++j) {
            f32x4 z = {0.f, 0.f, 0.f, 0.f};
            acc[i][j] = z;
        }

    f32x4    aE[4][2], aO[4][2];      // alternating A staging reg-sets (even/odd tiles)
    uint32_t breg[8], bregN[8];
    f16x2    ssv[4], zzv[4];
    float    s_nxt[4];
    uint32_t z_nxt[4];

    const int   ncb = n0 + wc * 64 + lr;
    const int   shz = 4 * (lr & 7);
    const float* xbase = x + (size_t)(m0 + arow) * K_DIM + acp * 8;

    const uint32_t* qp0 = qw + (size_t)lk * N_DIM + ncb;
    const uint32_t* qp1 = qp0 + (size_t)4 * N_DIM;

#define A_LOAD(S, KT) do { const float* ap_ = xbase + (KT) * BK;             \
    _Pragma("unroll") for (int i = 0; i < 4; ++i) {                          \
        const float* src_ = ap_ + (size_t)(i * 32) * K_DIM;                  \
        S[i][0] = *(const f32x4*)(src_);                                     \
        S[i][1] = *(const f32x4*)(src_ + 4); } } while (0)

#define A_WRITE(S, BUF) do {                                                 \
    _Pragma("unroll") for (int i = 0; i < 4; ++i) { H8 v_;                   \
        _Pragma("unroll") for (int j = 0; j < 4; ++j)                        \
            v_.p[j] = __builtin_bit_cast(f16x2,                              \
                __builtin_amdgcn_cvt_pkrtz(S[i][0][j], S[i][1][j]));         \
        *(f16x8*)&As[BUF][(arow + i * 32) * LDA + acp * 8] = v_.v; } } while (0)

#define LOADB() do {                                                         \
    _Pragma("unroll") for (int j = 0; j < 4; ++j) bregN[j]     = qp0[j * 16]; \
    _Pragma("unroll") for (int j = 0; j < 4; ++j) bregN[4 + j] = qp1[j * 16]; \
    qp0 += (size_t)8 * N_DIM; qp1 += (size_t)8 * N_DIM; } while (0)

#define COPYB() do { _Pragma("unroll") for (int q = 0; q < 8; ++q) breg[q] = bregN[q]; } while (0)

#define LOADSZ(g) do { _Pragma("unroll") for (int j = 0; j < 4; ++j) {       \
    s_nxt[j] = sc[(size_t)(g) * N_DIM + ncb + j * 16];                       \
    z_nxt[j] = qz[(size_t)(g) * NZW + (ncb >> 3) + j * 2]; } } while (0)

#define MAKESZ() do { _Pragma("unroll") for (int j = 0; j < 4; ++j) {        \
    _Float16 zh = (_Float16)(float)(1024u + ((z_nxt[j] >> shz) & 15u));      \
    _Float16 sh = (_Float16)s_nxt[j];                                        \
    f16x2 sp = {sh, sh}; ssv[j] = sp;                                        \
    f16x2 zp = {zh, zh}; zzv[j] = zp; } } while (0)

#define COMPUTE(BUF) do {                                                    \
    _Pragma("unroll") for (int ks = 0; ks < 2; ++ks) {                       \
        f16x8 af[4], bf[4];                                                  \
        _Pragma("unroll") for (int i = 0; i < 4; ++i)                        \
            af[i] = *(const f16x8*)&As[BUF][(wr * 64 + i * 16 + lr) * LDA + ks * 32 + lk * 8]; \
        _Pragma("unroll") for (int j = 0; j < 4; ++j)                        \
            bf[j] = dq_word(breg[ks * 4 + j], ssv[j], zzv[j]);               \
        _Pragma("unroll") for (int i = 0; i < 4; ++i)                        \
            _Pragma("unroll") for (int j = 0; j < 4; ++j)                    \
                acc[i][j] = __builtin_amdgcn_mfma_f32_16x16x32_f16(af[i], bf[j], acc[i][j], 0, 0, 0); \
    } } while (0)

    // ---------------- prologue ----------------
    LOADSZ(0);          // raw s/z for group 0
    A_LOAD(aE, 0);      // tile 0 -> even set
    LOADB();            // tile 0 -> bregN
    A_WRITE(aE, 0);     // tile 0 -> buf0 (prologue-only vmcnt wait)
    A_LOAD(aO, 1);      // tile 1 -> odd set (in flight across barrier)
    __syncthreads();

    for (int kt2 = 0; kt2 < NT / 2; ++kt2) {
        const int t0 = 2 * kt2;
        // ---- even tile t0 (buf0); stage tile t0+1 into buf1; load tile t0+2 ----
        MAKESZ();               // group kt2 (s/z loaded last odd phase / prologue)
        COPYB();                // breg = tile t0 fragments
        LOADB();                // tile t0+1 -> bregN (in flight during COMPUTE)
        A_WRITE(aO, 1);         // tile t0+1 -> buf1 (data loaded a full tile ago)
        if (kt2 + 1 < NT / 2) A_LOAD(aE, t0 + 2);
        COMPUTE(0);
        __syncthreads();

        // ---- odd tile t0+1 (buf1); stage tile t0+2 into buf0; load tile t0+3 ----
        COPYB();                // breg = tile t0+1 fragments
        if (kt2 + 1 < NT / 2) {
            LOADB();            // tile t0+2 -> bregN
            LOADSZ(kt2 + 1);    // raw s/z for next group
            A_WRITE(aE, 0);     // tile t0+2 -> buf0
            A_LOAD(aO, t0 + 3);
        }
        COMPUTE(1);
        __syncthreads();
    }

#undef A_LOAD
#undef A_WRITE
#undef LOADB
#undef COPYB
#undef LOADSZ
#undef MAKESZ
#undef COMPUTE

    // epilogue: C/D layout col = lane&15, row = (lane>>4)*4 + reg
    const int ccol0 = n0 + wc * 64 + lr;
    float bj[4];
#pragma unroll
    for (int j = 0; j < 4; ++j) bj[j] = bias[ccol0 + j * 16];
#pragma unroll
    for (int i = 0; i < 4; ++i) {
        const int rbase = m0 + wr * 64 + i * 16 + lk * 4;
#pragma unroll
        for (int j = 0; j < 4; ++j) {
            const int col = ccol0 + j * 16;
#pragma unroll
            for (int r = 0; r < 4; ++r)
                out[(size_t)(rbase + r) * N_DIM + col] = acc[i][j][r] + bj[j];
        }
    }
}

extern "C" void kernel_launch(void* const* d_in, const int* in_sizes, int n_in,
                              void* d_out, int out_size, void* d_ws, size_t ws_size,
                              hipStream_t stream) {
    const float*    xp = (const float*)d_in[0];
    const uint32_t* qw = (const uint32_t*)d_in[1];
    const uint32_t* qz = (const uint32_t*)d_in[2];
    const float*    sc = (const float*)d_in[3];
    const float*    bi = (const float*)d_in[4];
    float*          op = (float*)d_out;
    (void)in_sizes; (void)n_in; (void)d_ws; (void)ws_size; (void)out_size;

    qgemm_kernel<<<dim3(NWG), dim3(256), 0, stream>>>(xp, qw, qz, sc, bi, op);
}

// Round 7
// 957.964 us; speedup vs baseline: 4.1696x; 1.0461x over previous
//
#include <hip/hip_runtime.h>
#include <stdint.h>

#define K_DIM 4096
#define N_DIM 11008
#define M_DIM 8192

constexpr int BM = 128, BN = 128, BK = 64;
constexpr int LDA = 72;            // f16 elems/row: 144 B stride (R2-proven)
constexpr int NT  = K_DIM / BK;    // 64
constexpr int NZW = N_DIM / 8;     // 1376
constexpr int NXT = N_DIM / BN;    // 86
constexpr int MXT = M_DIM / BM;    // 64
constexpr int NWG = NXT * MXT;     // 5504 = 8 * 688

typedef _Float16 f16x2 __attribute__((ext_vector_type(2)));
typedef _Float16 f16x8 __attribute__((ext_vector_type(8)));
typedef float    f32x4 __attribute__((ext_vector_type(4)));
union H8 { f16x8 v; f16x2 p[4]; };

// word w holds nibbles for k-offsets 0..7; output k-order (0,4,1,5,2,6,3,7).
// Exact: (1024+q) - (1024+z) is Sterbenz-exact; single rounding on *s.
__device__ __forceinline__ f16x8 dq_word(uint32_t w, f16x2 ss, f16x2 zz) {
    H8 r;
    uint32_t t0 = ( w        & 0x000F000Fu) | 0x64006400u;
    uint32_t t1 = ((w >> 4)  & 0x000F000Fu) | 0x64006400u;
    uint32_t t2 = ((w >> 8)  & 0x000F000Fu) | 0x64006400u;
    uint32_t t3 = ((w >> 12) & 0x000F000Fu) | 0x64006400u;
    r.p[0] = (__builtin_bit_cast(f16x2, t0) - zz) * ss;
    r.p[1] = (__builtin_bit_cast(f16x2, t1) - zz) * ss;
    r.p[2] = (__builtin_bit_cast(f16x2, t2) - zz) * ss;
    r.p[3] = (__builtin_bit_cast(f16x2, t3) - zz) * ss;
    return r.v;
}

// Barrier WITHOUT vmcnt(0) drain: lgkmcnt(0) guarantees this wave's ds_writes
// are visible, s_barrier syncs the block, sched_barrier(0) stops the scheduler
// hoisting post-barrier LDS reads above it (rule #18). Global prefetch loads
// stay in flight across the barrier (T4); the compiler inserts counted vmcnt
// before their consumers.
#define BAR() do {                                           \
    asm volatile("s_waitcnt lgkmcnt(0)" ::: "memory");       \
    __builtin_amdgcn_s_barrier();                            \
    __builtin_amdgcn_sched_barrier(0);                       \
} while (0)

// ===== R6 structure (dbuf, 1 barrier/tile, T14 split) + no-drain barriers =====
__global__ __launch_bounds__(256, 3)
void qgemm_kernel(const float* __restrict__ x, const uint32_t* __restrict__ qw,
                  const uint32_t* __restrict__ qz, const float* __restrict__ sc,
                  const float* __restrict__ bias, float* __restrict__ out)
{
    __shared__ _Float16 As[2][BM * LDA];   // 2 x 18 KiB

    const int tid  = threadIdx.x;
    const int lid  = (blockIdx.x & 7) * (NWG / 8) + (blockIdx.x >> 3); // XCD swizzle
    const int m0   = (lid / NXT) * BM;
    const int n0   = (lid % NXT) * BN;

    const int lane = tid & 63, wid = tid >> 6;
    const int wr = wid >> 1, wc = wid & 1;
    const int lr = lane & 15, lk = lane >> 4;

    const int arow = tid >> 3;        // A staging row (0..31, +i*32)
    const int acp  = tid & 7;         // A staging col-octet

    f32x4 acc[4][4];
#pragma unroll
    for (int i = 0; i < 4; ++i)
#pragma unroll
        for (int j = 0; j < 4; ++j) {
            f32x4 z = {0.f, 0.f, 0.f, 0.f};
            acc[i][j] = z;
        }

    f32x4    aE[4][2], aO[4][2];      // alternating A staging reg-sets (even/odd tiles)
    uint32_t breg[8], bregN[8];
    f16x2    ssv[4], zzv[4];
    float    s_nxt[4];
    uint32_t z_nxt[4];

    const int   ncb = n0 + wc * 64 + lr;
    const int   shz = 4 * (lr & 7);
    const float* xbase = x + (size_t)(m0 + arow) * K_DIM + acp * 8;

    const uint32_t* qp0 = qw + (size_t)lk * N_DIM + ncb;
    const uint32_t* qp1 = qp0 + (size_t)4 * N_DIM;

#define A_LOAD(S, KT) do { const float* ap_ = xbase + (KT) * BK;             \
    _Pragma("unroll") for (int i = 0; i < 4; ++i) {                          \
        const float* src_ = ap_ + (size_t)(i * 32) * K_DIM;                  \
        S[i][0] = *(const f32x4*)(src_);                                     \
        S[i][1] = *(const f32x4*)(src_ + 4); } } while (0)

#define A_WRITE(S, BUF) do {                                                 \
    _Pragma("unroll") for (int i = 0; i < 4; ++i) { H8 v_;                   \
        _Pragma("unroll") for (int j = 0; j < 4; ++j)                        \
            v_.p[j] = __builtin_bit_cast(f16x2,                              \
                __builtin_amdgcn_cvt_pkrtz(S[i][0][j], S[i][1][j]));         \
        *(f16x8*)&As[BUF][(arow + i * 32) * LDA + acp * 8] = v_.v; } } while (0)

#define LOADB() do {                                                         \
    _Pragma("unroll") for (int j = 0; j < 4; ++j) bregN[j]     = qp0[j * 16]; \
    _Pragma("unroll") for (int j = 0; j < 4; ++j) bregN[4 + j] = qp1[j * 16]; \
    qp0 += (size_t)8 * N_DIM; qp1 += (size_t)8 * N_DIM; } while (0)

#define COPYB() do { _Pragma("unroll") for (int q = 0; q < 8; ++q) breg[q] = bregN[q]; } while (0)

#define LOADSZ(g) do { _Pragma("unroll") for (int j = 0; j < 4; ++j) {       \
    s_nxt[j] = sc[(size_t)(g) * N_DIM + ncb + j * 16];                       \
    z_nxt[j] = qz[(size_t)(g) * NZW + (ncb >> 3) + j * 2]; } } while (0)

#define MAKESZ() do { _Pragma("unroll") for (int j = 0; j < 4; ++j) {        \
    _Float16 zh = (_Float16)(float)(1024u + ((z_nxt[j] >> shz) & 15u));      \
    _Float16 sh = (_Float16)s_nxt[j];                                        \
    f16x2 sp = {sh, sh}; ssv[j] = sp;                                        \
    f16x2 zp = {zh, zh}; zzv[j] = zp; } } while (0)

#define COMPUTE(BUF) do {                                                    \
    _Pragma("unroll") for (int ks = 0; ks < 2; ++ks) {                       \
        f16x8 af[4], bf[4];                                                  \
        _Pragma("unroll") for (int i = 0; i < 4; ++i)                        \
            af[i] = *(const f16x8*)&As[BUF][(wr * 64 + i * 16 + lr) * LDA + ks * 32 + lk * 8]; \
        _Pragma("unroll") for (int j = 0; j < 4; ++j)                        \
            bf[j] = dq_word(breg[ks * 4 + j], ssv[j], zzv[j]);               \
        _Pragma("unroll") for (int i = 0; i < 4; ++i)                        \
            _Pragma("unroll") for (int j = 0; j < 4; ++j)                    \
                acc[i][j] = __builtin_amdgcn_mfma_f32_16x16x32_f16(af[i], bf[j], acc[i][j], 0, 0, 0); \
    } } while (0)

    // ---------------- prologue ----------------
    LOADSZ(0);          // raw s/z for group 0
    A_LOAD(aE, 0);      // tile 0 -> even set
    LOADB();            // tile 0 -> bregN
    A_WRITE(aE, 0);     // tile 0 -> buf0
    A_LOAD(aO, 1);      // tile 1 -> odd set (in flight across barrier)
    BAR();

    for (int kt2 = 0; kt2 < NT / 2; ++kt2) {
        const int t0 = 2 * kt2;
        // ---- even tile t0 (buf0); stage tile t0+1 into buf1; load tile t0+2 ----
        MAKESZ();               // group kt2 (s/z loaded last odd phase / prologue)
        COPYB();                // breg = tile t0 fragments
        LOADB();                // tile t0+1 -> bregN (in flight during COMPUTE)
        A_WRITE(aO, 1);         // tile t0+1 -> buf1 (data loaded a full tile ago)
        if (kt2 + 1 < NT / 2) A_LOAD(aE, t0 + 2);
        COMPUTE(0);
        BAR();

        // ---- odd tile t0+1 (buf1); stage tile t0+2 into buf0; load tile t0+3 ----
        COPYB();                // breg = tile t0+1 fragments
        if (kt2 + 1 < NT / 2) {
            LOADB();            // tile t0+2 -> bregN
            LOADSZ(kt2 + 1);    // raw s/z for next group
            A_WRITE(aE, 0);     // tile t0+2 -> buf0
            A_LOAD(aO, t0 + 3);
        }
        COMPUTE(1);
        BAR();
    }

#undef A_LOAD
#undef A_WRITE
#undef LOADB
#undef COPYB
#undef LOADSZ
#undef MAKESZ
#undef COMPUTE

    // epilogue: C/D layout col = lane&15, row = (lane>>4)*4 + reg
    const int ccol0 = n0 + wc * 64 + lr;
    float bj[4];
#pragma unroll
    for (int j = 0; j < 4; ++j) bj[j] = bias[ccol0 + j * 16];
#pragma unroll
    for (int i = 0; i < 4; ++i) {
        const int rbase = m0 + wr * 64 + i * 16 + lk * 4;
#pragma unroll
        for (int j = 0; j < 4; ++j) {
            const int col = ccol0 + j * 16;
#pragma unroll
            for (int r = 0; r < 4; ++r)
                out[(size_t)(rbase + r) * N_DIM + col] = acc[i][j][r] + bj[j];
        }
    }
}

extern "C" void kernel_launch(void* const* d_in, const int* in_sizes, int n_in,
                              void* d_out, int out_size, void* d_ws, size_t ws_size,
                              hipStream_t stream) {
    const float*    xp = (const float*)d_in[0];
    const uint32_t* qw = (const uint32_t*)d_in[1];
    const uint32_t* qz = (const uint32_t*)d_in[2];
    const float*    sc = (const float*)d_in[3];
    const float*    bi = (const float*)d_in[4];
    float*          op = (float*)d_out;
    (void)in_sizes; (void)n_in; (void)d_ws; (void)ws_size; (void)out_size;

    qgemm_kernel<<<dim3(NWG), dim3(256), 0, stream>>>(xp, qw, qz, sc, bi, op);
}